// Round 14
// baseline (156.795 us; speedup 1.0000x reference)
//
#include <hip/hip_runtime.h>
#include <hip/hip_bf16.h>
#include <stdint.h>

#define B_N   16384
#define L_N   63
#define K2LOG2E 2.8853900817779268f   // 2*log2(e)
#define LOG2E   1.4426950408889634f

typedef unsigned int   u32;
typedef unsigned short u16;
typedef __attribute__((ext_vector_type(8))) __bf16 bf16x8;
typedef __attribute__((ext_vector_type(4))) float  f32x4;

__device__ __forceinline__ u16 f2b(float f){
  u32 u = __builtin_bit_cast(u32, f);
  u += 0x7fffu + ((u >> 16) & 1u);
  return (u16)(u >> 16);
}
__device__ __forceinline__ u32 pk_bf16(float lo, float hi){
  u32 r;
  asm("v_cvt_pk_bf16_f32 %0, %1, %2" : "=v"(r) : "v"(lo), "v"(hi));
  return r;
}
// tanh with 2*log2(e) pre-baked into weights: acc = 2log2e*(Wx+b)
// tanh = 1 - 2/(exp2(acc)+1). 2 VALU + 2 trans, saturation-safe.
__device__ __forceinline__ float tanh_sc(float acc){
  float t = __builtin_amdgcn_exp2f(acc);
  float r = __builtin_amdgcn_rcpf(t + 1.0f);
  return fmaf(-2.0f, r, 1.0f);
}

// ---- merged prep: blocks [0,63) convert weights for layer l=bid;
// blocks [63,1087) convert x (f32 -> bf16, col63 := 1.0).
__global__ void k_prep(const float* __restrict__ W1, const float* __restrict__ b1,
                       const float* __restrict__ W2, const float* __restrict__ b2,
                       const float* __restrict__ x,
                       u16* __restrict__ w1t, u16* __restrict__ w2t,
                       u16* __restrict__ xbf){
  const int bid = blockIdx.x, tid = threadIdx.x;
  if (bid >= L_N){
    int idx = (bid - L_N)*256 + tid;       // covers B_N*64/4 = 262144 exactly
    float4 v = ((const float4*)x)[idx];
    ushort4 r;
    r.x = f2b(v.x); r.y = f2b(v.y); r.z = f2b(v.z);
    r.w = ((idx & 15) == 15) ? (u16)0x3F80 : f2b(v.w);
    ((ushort4*)xbf)[idx] = r;
    return;
  }
  __shared__ u16 t[128*160];
  const int l = bid;
  #pragma unroll
  for (int i = 0; i < 32; ++i) t[i*256 + tid] = 0;
  __syncthreads();
  for (int i = 0; i < 32; ++i){
    int idx = i*256 + tid;              // idx = d*128 + n (coalesced)
    if (idx < 63*128){
      int d = idx >> 7, n = idx & 127;
      if (d <= l) t[n*64 + d] = f2b(W1[(l*63 + d)*128 + n] * K2LOG2E);
    }
  }
  if (tid < 128) t[tid*64 + 63] = f2b(b1[l*128 + tid] * K2LOG2E);
  __syncthreads();
  {
    uint4* o = (uint4*)(w1t + l*(128*64));
    const uint4* s4 = (const uint4*)t;
    #pragma unroll
    for (int i = 0; i < 4; ++i) o[i*256 + tid] = s4[i*256 + tid];
  }
  __syncthreads();
  #pragma unroll
  for (int i = 0; i < 80; ++i) t[i*256 + tid] = 0;
  __syncthreads();
  #pragma unroll
  for (int i = 0; i < 64; ++i){
    int idx = i*256 + tid;              // idx = h*128 + n (coalesced)
    int h = idx >> 7, n = idx & 127;
    t[n*160 + h] = f2b(W2[l*16384 + idx] * K2LOG2E);
  }
  if (tid < 128) t[tid*160 + 128] = f2b(b2[l*128 + tid] * K2LOG2E);
  __syncthreads();
  {
    uint4* o = (uint4*)(w2t + l*(128*160));
    const uint4* s4 = (const uint4*)t;
    #pragma unroll
    for (int i = 0; i < 10; ++i) o[i*256 + tid] = s4[i*256 + tid];
  }
}

// ---- main: R13 structure (128 rows x layer, 4 waves, bt-split halves,
// prescaled weights, b2 via K=160 slice, stage-2 prefetch, sc aliased in
// h1b, LDS exactly 32KB) + (256,5) reg cap (102 unified) for 5 blocks/CU,
// with W3 coeff loads deferred into the epilogues to shorten live ranges.
__global__ __launch_bounds__(256, 5)
void k_main(const u16* __restrict__ W1T, const u16* __restrict__ W2T,
            const u16* __restrict__ xbf, const float* __restrict__ x,
            const float* __restrict__ W3, const float* __restrict__ b3,
            float* __restrict__ out, float* __restrict__ alph)
{
  __shared__ __align__(16) char h1b[32768];   // h1 [128b][256B] swizzled;
                                              // first 4KB reused as sc after barrier 2
  const int tid = threadIdx.x;
  const int l  = blockIdx.y;
  const int bx = blockIdx.x;
  const int wv = tid >> 6;
  const int ln = tid & 63;
  const int c  = ln & 15;
  const int g  = ln >> 4;
  const int rowbase = bx*128;
  const int sx = (c & 7) << 4;         // row-swizzle XOR ((b&7)==(c&7))

  const u16* w1p = W1T + l*(128*64);
  const u16* w2p = W2T + l*(128*160);

  bf16x8 a1f[2][2];
  #pragma unroll
  for (int m = 0; m < 2; ++m)
    #pragma unroll
    for (int s = 0; s < 2; ++s)
      a1f[m][s] = *(const bf16x8*)(w1p + ((2*wv+m)*16 + c)*64 + s*32 + g*8);

  // stage-2 A-fragment prefetch registers (filled below, pre-barrier)
  bf16x8 a2[2][4];

  // ---- stage 1, half 0 (bt 0..3): MFMA ----
  {
    f32x4 acc[2][4] = {};
    #pragma unroll
    for (int s = 0; s < 2; ++s)
      #pragma unroll
      for (int bt = 0; bt < 4; ++bt){
        bf16x8 xf = *(const bf16x8*)(xbf + (size_t)(rowbase + bt*16 + c)*64 + s*32 + g*8);
        acc[0][bt] = __builtin_amdgcn_mfma_f32_16x16x32_bf16(a1f[0][s], xf, acc[0][bt], 0,0,0);
        acc[1][bt] = __builtin_amdgcn_mfma_f32_16x16x32_bf16(a1f[1][s], xf, acc[1][bt], 0,0,0);
      }

    // prefetch stage-2 s=0,1 A-frags: h1-independent; L2 latency hides
    // under both epilogue halves + the barrier.
    #pragma unroll
    for (int m = 0; m < 2; ++m)
      #pragma unroll
      for (int s = 0; s < 2; ++s)
        a2[m][s] = *(const bf16x8*)(w2p + ((2*wv+m)*16 + c)*160 + s*32 + g*8);

    // epilogue 1, half 0
    #pragma unroll
    for (int m = 0; m < 2; ++m){
      int h0 = (2*wv+m)*16 + g*4;
      #pragma unroll
      for (int bt = 0; bt < 4; ++bt){
        u32 p0 = pk_bf16(tanh_sc(acc[m][bt][0]), tanh_sc(acc[m][bt][1]));
        u32 p1 = pk_bf16(tanh_sc(acc[m][bt][2]), tanh_sc(acc[m][bt][3]));
        int b = bt*16 + c;
        *(uint2*)(h1b + b*256 + ((h0*2) ^ sx)) = make_uint2(p0, p1);
      }
    }
  }
  // ---- stage 1, half 1 (bt 4..7): MFMA + epilogue ----
  {
    f32x4 acc[2][4] = {};
    #pragma unroll
    for (int s = 0; s < 2; ++s)
      #pragma unroll
      for (int bt = 0; bt < 4; ++bt){
        bf16x8 xf = *(const bf16x8*)(xbf + (size_t)(rowbase + (bt+4)*16 + c)*64 + s*32 + g*8);
        acc[0][bt] = __builtin_amdgcn_mfma_f32_16x16x32_bf16(a1f[0][s], xf, acc[0][bt], 0,0,0);
        acc[1][bt] = __builtin_amdgcn_mfma_f32_16x16x32_bf16(a1f[1][s], xf, acc[1][bt], 0,0,0);
      }
    #pragma unroll
    for (int m = 0; m < 2; ++m){
      int h0 = (2*wv+m)*16 + g*4;
      #pragma unroll
      for (int bt = 0; bt < 4; ++bt){
        u32 p0 = pk_bf16(tanh_sc(acc[m][bt][0]), tanh_sc(acc[m][bt][1]));
        u32 p1 = pk_bf16(tanh_sc(acc[m][bt][2]), tanh_sc(acc[m][bt][3]));
        int b = (bt+4)*16 + c;
        *(uint2*)(h1b + b*256 + ((h0*2) ^ sx)) = make_uint2(p0, p1);
      }
    }
  }
  __syncthreads();                       // barrier 1: h1 complete

  // complete A-fragment set (s=2,3 + bias slice); overlaps first MFMAs
  #pragma unroll
  for (int m = 0; m < 2; ++m)
    #pragma unroll
    for (int s = 2; s < 4; ++s)
      a2[m][s] = *(const bf16x8*)(w2p + ((2*wv+m)*16 + c)*160 + s*32 + g*8);
  bf16x8 ab[2];
  #pragma unroll
  for (int m = 0; m < 2; ++m)
    ab[m] = *(const bf16x8*)(w2p + ((2*wv+m)*16 + c)*160 + 128 + g*8);
  uint4 cw; cw.x = (g == 0) ? 0x00003F80u : 0u; cw.y = cw.z = cw.w = 0u;
  const bf16x8 cf = __builtin_bit_cast(bf16x8, cw);

  // ---- stage 2 + 3 in two bt=4 halves: half-B MFMAs overlap half-A tanh ----
  float part[8][2] = {};
  #pragma unroll
  for (int half = 0; half < 2; ++half){
    f32x4 acc2[2][4] = {};
    #pragma unroll
    for (int s = 0; s < 4; ++s)
      #pragma unroll
      for (int bt = 0; bt < 4; ++bt){
        int b = (half*4 + bt)*16 + c;
        bf16x8 hf = *(const bf16x8*)(h1b + b*256 + ((s*64 + g*16) ^ sx));
        acc2[0][bt] = __builtin_amdgcn_mfma_f32_16x16x32_bf16(a2[0][s], hf, acc2[0][bt], 0,0,0);
        acc2[1][bt] = __builtin_amdgcn_mfma_f32_16x16x32_bf16(a2[1][s], hf, acc2[1][bt], 0,0,0);
      }
    #pragma unroll
    for (int bt = 0; bt < 4; ++bt){
      acc2[0][bt] = __builtin_amdgcn_mfma_f32_16x16x32_bf16(ab[0], cf, acc2[0][bt], 0,0,0);
      acc2[1][bt] = __builtin_amdgcn_mfma_f32_16x16x32_bf16(ab[1], cf, acc2[1][bt], 0,0,0);
    }
    // epilogue: tanh + W3 dot into part; W3 coeffs loaded here (short live
    // range; L2/L1-hot, latency covered by the extra resident waves)
    #pragma unroll
    for (int m = 0; m < 2; ++m){
      int q = (2*wv+m)*4 + g;                    // row-quad index n0/4
      float4 w3a = ((const float4*)(W3 + l*256))[q*2 + 0];
      float4 w3b = ((const float4*)(W3 + l*256))[q*2 + 1];
      float w30[4] = { w3a.x, w3a.z, w3b.x, w3b.z };
      float w31[4] = { w3a.y, w3a.w, w3b.y, w3b.w };
      #pragma unroll
      for (int bt = 0; bt < 4; ++bt)
        #pragma unroll
        for (int r = 0; r < 4; ++r){
          float h2 = tanh_sc(acc2[m][bt][r]);
          part[half*4+bt][0] = fmaf(h2, w30[r], part[half*4+bt][0]);
          part[half*4+bt][1] = fmaf(h2, w31[r], part[half*4+bt][1]);
        }
    }
  }

  // reduce the 4 g-groups
  #pragma unroll
  for (int bt = 0; bt < 8; ++bt){
    float v0 = part[bt][0], v1 = part[bt][1];
    v0 += __shfl_xor(v0, 16, 64); v0 += __shfl_xor(v0, 32, 64);
    v1 += __shfl_xor(v1, 16, 64); v1 += __shfl_xor(v1, 32, 64);
    part[bt][0] = v0; part[bt][1] = v1;
  }
  __syncthreads();                       // barrier 2: all h1 reads done (alias safety)
  float2* const sc = (float2*)h1b;       // sc[4][128] aliases h1's first 4KB
  if (g == 0){
    #pragma unroll
    for (int bt = 0; bt < 8; ++bt)
      sc[wv*128 + bt*16 + c] = make_float2(part[bt][0], part[bt][1]);
  }
  __syncthreads();                       // barrier 3: sc visible

  // tail: finish mu/alpha, fuse z-store (reversed), save alpha for logdet
  if (tid < 128){
    int row = rowbase + tid;
    float2 s0 = sc[tid], s1 = sc[128+tid], s2 = sc[256+tid], s3 = sc[384+tid];
    float muv = s0.x + s1.x + s2.x + s3.x + b3[l*2 + 0];
    float alv = s0.y + s1.y + s2.y + s3.y + b3[l*2 + 1];
    float xv  = x[(size_t)row*64 + l + 1];
    out[(size_t)row*64 + 62 - l] = (xv - muv) * __builtin_amdgcn_exp2f(-alv * LOG2E);
    alph[(size_t)row*64 + l + 1] = alv;
  }
}

// ---- finalize: z column 63 (d=0 term) + logdet row-reduce ----
__global__ void k_fin(const float* __restrict__ x, const float* __restrict__ alph,
                      const float* __restrict__ ip, float* __restrict__ out)
{
  int row = blockIdx.x*4 + (threadIdx.x >> 6);
  int d   = threadIdx.x & 63;
  float a = (d == 0) ? ip[1] : alph[(size_t)row*64 + d];
  float s = a;
  #pragma unroll
  for (int off = 32; off; off >>= 1) s += __shfl_xor(s, off, 64);
  if (d == 0){
    out[(size_t)row*64 + 63] = (x[(size_t)row*64] - ip[0]) * __builtin_amdgcn_exp2f(-a * LOG2E);
    out[(size_t)B_N*64 + row] = -s;
  }
}

extern "C" void kernel_launch(void* const* d_in, const int* in_sizes, int n_in,
                              void* d_out, int out_size, void* d_ws, size_t ws_size,
                              hipStream_t stream)
{
  const float* x  = (const float*)d_in[0];
  const float* W1 = (const float*)d_in[1];
  const float* b1 = (const float*)d_in[2];
  const float* W2 = (const float*)d_in[3];
  const float* b2 = (const float*)d_in[4];
  const float* W3 = (const float*)d_in[5];
  const float* b3 = (const float*)d_in[6];
  const float* ip = (const float*)d_in[7];

  char* ws = (char*)d_ws;
  // w1t 1.0MB@0 | w2t 2.46MB@1MB | xbf 2MB@3.5MB | alph 4MB@5.5MB
  u16*   w1t  = (u16*)(ws);
  u16*   w2t  = (u16*)(ws + 1048576);
  u16*   xbf  = (u16*)(ws + 3670016);
  float* alph = (float*)(ws + 5767168);
  if (ws_size < 9961472) return;  // fail visibly rather than corrupt

  k_prep<<<L_N + (B_N*64/4)/256, 256, 0, stream>>>(W1, b1, W2, b2, x,
                                                   w1t, w2t, xbf);

  dim3 grid(B_N/128, L_N);
  k_main<<<grid, 256, 0, stream>>>(w1t, w2t, xbf, x, W3, b3,
                                   (float*)d_out, alph);

  k_fin<<<B_N/4, 256, 0, stream>>>(x, alph, ip, (float*)d_out);
}

// Round 15
// 133.285 us; speedup vs baseline: 1.1764x; 1.1764x over previous
//
#include <hip/hip_runtime.h>
#include <hip/hip_bf16.h>
#include <stdint.h>

#define B_N   16384
#define L_N   63
#define K2LOG2E 2.8853900817779268f   // 2*log2(e)
#define LOG2E   1.4426950408889634f

typedef unsigned int   u32;
typedef unsigned short u16;
typedef __attribute__((ext_vector_type(8))) __bf16 bf16x8;
typedef __attribute__((ext_vector_type(4))) float  f32x4;

__device__ __forceinline__ u16 f2b(float f){
  u32 u = __builtin_bit_cast(u32, f);
  u += 0x7fffu + ((u >> 16) & 1u);
  return (u16)(u >> 16);
}
__device__ __forceinline__ u32 pk_bf16(float lo, float hi){
  u32 r;
  asm("v_cvt_pk_bf16_f32 %0, %1, %2" : "=v"(r) : "v"(lo), "v"(hi));
  return r;
}
// tanh with 2*log2(e) pre-baked into weights: acc = 2log2e*(Wx+b)
// tanh = 1 - 2/(exp2(acc)+1). 2 VALU + 2 trans, saturation-safe.
__device__ __forceinline__ float tanh_sc(float acc){
  float t = __builtin_amdgcn_exp2f(acc);
  float r = __builtin_amdgcn_rcpf(t + 1.0f);
  return fmaf(-2.0f, r, 1.0f);
}

// ---- merged prep: blocks [0,63) convert weights for layer l=bid;
// blocks [63,1087) convert x (f32 -> bf16, col63 := 1.0).
// w1t[l][n][64]*K2LOG2E (col63 = b1*K); w2t[l][n][160]*K2LOG2E (k128 = b2*K).
__global__ void k_prep(const float* __restrict__ W1, const float* __restrict__ b1,
                       const float* __restrict__ W2, const float* __restrict__ b2,
                       const float* __restrict__ x,
                       u16* __restrict__ w1t, u16* __restrict__ w2t,
                       u16* __restrict__ xbf){
  const int bid = blockIdx.x, tid = threadIdx.x;
  if (bid >= L_N){
    int idx = (bid - L_N)*256 + tid;       // covers B_N*64/4 = 262144 exactly
    float4 v = ((const float4*)x)[idx];
    ushort4 r;
    r.x = f2b(v.x); r.y = f2b(v.y); r.z = f2b(v.z);
    r.w = ((idx & 15) == 15) ? (u16)0x3F80 : f2b(v.w);
    ((ushort4*)xbf)[idx] = r;
    return;
  }
  __shared__ u16 t[128*160];
  const int l = bid;
  // --- W1: [d][n] masked d<=l -> [n][64], col63 = b1 ---
  #pragma unroll
  for (int i = 0; i < 32; ++i) t[i*256 + tid] = 0;
  __syncthreads();
  for (int i = 0; i < 32; ++i){
    int idx = i*256 + tid;              // idx = d*128 + n (coalesced)
    if (idx < 63*128){
      int d = idx >> 7, n = idx & 127;
      if (d <= l) t[n*64 + d] = f2b(W1[(l*63 + d)*128 + n] * K2LOG2E);
    }
  }
  if (tid < 128) t[tid*64 + 63] = f2b(b1[l*128 + tid] * K2LOG2E);
  __syncthreads();
  {
    uint4* o = (uint4*)(w1t + l*(128*64));
    const uint4* s4 = (const uint4*)t;
    #pragma unroll
    for (int i = 0; i < 4; ++i) o[i*256 + tid] = s4[i*256 + tid];
  }
  __syncthreads();
  // --- W2: [h][n] -> [n][160], k128 = b2, rest 0 ---
  #pragma unroll
  for (int i = 0; i < 80; ++i) t[i*256 + tid] = 0;
  __syncthreads();
  #pragma unroll
  for (int i = 0; i < 64; ++i){
    int idx = i*256 + tid;              // idx = h*128 + n (coalesced)
    int h = idx >> 7, n = idx & 127;
    t[n*160 + h] = f2b(W2[l*16384 + idx] * K2LOG2E);
  }
  if (tid < 128) t[tid*160 + 128] = f2b(b2[l*128 + tid] * K2LOG2E);
  __syncthreads();
  {
    uint4* o = (uint4*)(w2t + l*(128*160));
    const uint4* s4 = (const uint4*)t;
    #pragma unroll
    for (int i = 0; i < 10; ++i) o[i*256 + tid] = s4[i*256 + tid];
  }
}

// ---- main: R5 geometry (128 rows x layer l, 4 waves own h-row M-tiles,
// bt=8), prescaled weights, b2 via K=160 MFMA slice, and stage-2 weight +
// W3 prefetch issued BEFORE epilogue-1 so L2 latency hides under tanh work
// and the barrier. 2 barriers, stage-3 = VALU dot, no atomics, no spill.
__global__ __launch_bounds__(256, 4)
void k_main(const u16* __restrict__ W1T, const u16* __restrict__ W2T,
            const u16* __restrict__ xbf, const float* __restrict__ x,
            const float* __restrict__ W3, const float* __restrict__ b3,
            float* __restrict__ out, float* __restrict__ alph)
{
  __shared__ __align__(16) u16 h1[128*128];   // [b][h] swizzled, 32KB
  __shared__ float2 sc[4][128];               // stage-3 partials, 4KB
  const int tid = threadIdx.x;
  const int l  = blockIdx.y;
  const int bx = blockIdx.x;
  const int wv = tid >> 6;
  const int ln = tid & 63;
  const int c  = ln & 15;
  const int g  = ln >> 4;
  const int rowbase = bx*128;
  const int sx = (c & 7) << 4;         // row-swizzle XOR ((b&7)==(c&7))
  char* const h1b = (char*)h1;

  const u16* w1p = W1T + l*(128*64);
  const u16* w2p = W2T + l*(128*160);

  // ---- stage 1: h1T[h][b] = tanh(K*(W1T.xT))  (b1 in col 63, x col63=1) ----
  bf16x8 a1f[2][2];
  #pragma unroll
  for (int m = 0; m < 2; ++m)
    #pragma unroll
    for (int s = 0; s < 2; ++s)
      a1f[m][s] = *(const bf16x8*)(w1p + ((2*wv+m)*16 + c)*64 + s*32 + g*8);

  f32x4 acc[2][8] = {};
  #pragma unroll
  for (int s = 0; s < 2; ++s)
    #pragma unroll
    for (int bt = 0; bt < 8; ++bt){
      bf16x8 xf = *(const bf16x8*)(xbf + (size_t)(rowbase + bt*16 + c)*64 + s*32 + g*8);
      acc[0][bt] = __builtin_amdgcn_mfma_f32_16x16x32_bf16(a1f[0][s], xf, acc[0][bt], 0,0,0);
      acc[1][bt] = __builtin_amdgcn_mfma_f32_16x16x32_bf16(a1f[1][s], xf, acc[1][bt], 0,0,0);
    }

  // ---- prefetch stage-2 s=0,1 A-fragments + W3 coefficients NOW: these
  // loads are h1-independent; their L2 latency hides under epilogue-1 tanh
  // work and the barrier (loads cannot be hoisted across __syncthreads).
  bf16x8 a2[2][4];
  #pragma unroll
  for (int m = 0; m < 2; ++m)
    #pragma unroll
    for (int s = 0; s < 2; ++s)
      a2[m][s] = *(const bf16x8*)(w2p + ((2*wv+m)*16 + c)*160 + s*32 + g*8);
  float w30[2][4], w31[2][4];
  #pragma unroll
  for (int m = 0; m < 2; ++m){
    int q = (2*wv+m)*4 + g;                    // row-quad index n0/4
    float4 w3a = ((const float4*)(W3 + l*256))[q*2 + 0];
    float4 w3b = ((const float4*)(W3 + l*256))[q*2 + 1];
    w30[m][0]=w3a.x; w30[m][1]=w3a.z; w30[m][2]=w3b.x; w30[m][3]=w3b.z;
    w31[m][0]=w3a.y; w31[m][1]=w3a.w; w31[m][2]=w3b.y; w31[m][3]=w3b.w;
  }

  // epilogue 1: tanh, pack, swizzled 8B store into h1[b][h]
  #pragma unroll
  for (int m = 0; m < 2; ++m){
    int h0 = (2*wv+m)*16 + g*4;
    #pragma unroll
    for (int bt = 0; bt < 8; ++bt){
      u32 p0 = pk_bf16(tanh_sc(acc[m][bt][0]), tanh_sc(acc[m][bt][1]));
      u32 p1 = pk_bf16(tanh_sc(acc[m][bt][2]), tanh_sc(acc[m][bt][3]));
      int b = bt*16 + c;
      *(uint2*)(h1b + b*256 + ((h0*2) ^ sx)) = make_uint2(p0, p1);
    }
  }
  __syncthreads();

  // complete the A-fragment set (s=2,3 + bias slice) right after the barrier;
  // these overlap the first s=0,1 MFMAs which use prefetched fragments.
  #pragma unroll
  for (int m = 0; m < 2; ++m)
    #pragma unroll
    for (int s = 2; s < 4; ++s)
      a2[m][s] = *(const bf16x8*)(w2p + ((2*wv+m)*16 + c)*160 + s*32 + g*8);
  bf16x8 ab[2];
  #pragma unroll
  for (int m = 0; m < 2; ++m)
    ab[m] = *(const bf16x8*)(w2p + ((2*wv+m)*16 + c)*160 + 128 + g*8);
  uint4 cw; cw.x = (g == 0) ? 0x00003F80u : 0u; cw.y = cw.z = cw.w = 0u;
  const bf16x8 cf = __builtin_bit_cast(bf16x8, cw);

  // ---- stage 2: acc2 = K*(W2T.h1T + b2) ----
  f32x4 acc2[2][8] = {};
  #pragma unroll
  for (int s = 0; s < 4; ++s){
    #pragma unroll
    for (int bt = 0; bt < 8; ++bt){
      int b = bt*16 + c;
      bf16x8 hf = *(const bf16x8*)(h1b + b*256 + ((s*64 + g*16) ^ sx));
      acc2[0][bt] = __builtin_amdgcn_mfma_f32_16x16x32_bf16(a2[0][s], hf, acc2[0][bt], 0,0,0);
      acc2[1][bt] = __builtin_amdgcn_mfma_f32_16x16x32_bf16(a2[1][s], hf, acc2[1][bt], 0,0,0);
    }
  }
  #pragma unroll
  for (int bt = 0; bt < 8; ++bt){
    acc2[0][bt] = __builtin_amdgcn_mfma_f32_16x16x32_bf16(ab[0], cf, acc2[0][bt], 0,0,0);
    acc2[1][bt] = __builtin_amdgcn_mfma_f32_16x16x32_bf16(ab[1], cf, acc2[1][bt], 0,0,0);
  }

  // epilogue 2 + stage 3: tanh(acc2), dot W3, per-wave partials
  float part[8][2] = {};
  #pragma unroll
  for (int m = 0; m < 2; ++m)
    #pragma unroll
    for (int bt = 0; bt < 8; ++bt)
      #pragma unroll
      for (int r = 0; r < 4; ++r){
        float h2 = tanh_sc(acc2[m][bt][r]);
        part[bt][0] = fmaf(h2, w30[m][r], part[bt][0]);
        part[bt][1] = fmaf(h2, w31[m][r], part[bt][1]);
      }
  #pragma unroll
  for (int bt = 0; bt < 8; ++bt){
    float v0 = part[bt][0], v1 = part[bt][1];
    v0 += __shfl_xor(v0, 16, 64); v0 += __shfl_xor(v0, 32, 64);
    v1 += __shfl_xor(v1, 16, 64); v1 += __shfl_xor(v1, 32, 64);
    part[bt][0] = v0; part[bt][1] = v1;
  }
  if (g == 0){
    #pragma unroll
    for (int bt = 0; bt < 8; ++bt)
      sc[wv][bt*16 + c] = make_float2(part[bt][0], part[bt][1]);
  }
  __syncthreads();

  // tail: finish mu/alpha, fuse z-store (reversed), save alpha for logdet
  if (tid < 128){
    int row = rowbase + tid;
    float2 s0 = sc[0][tid], s1 = sc[1][tid], s2 = sc[2][tid], s3 = sc[3][tid];
    float muv = s0.x + s1.x + s2.x + s3.x + b3[l*2 + 0];
    float alv = s0.y + s1.y + s2.y + s3.y + b3[l*2 + 1];
    float xv  = x[(size_t)row*64 + l + 1];
    out[(size_t)row*64 + 62 - l] = (xv - muv) * __builtin_amdgcn_exp2f(-alv * LOG2E);
    alph[(size_t)row*64 + l + 1] = alv;
  }
}

// ---- finalize: z column 63 (d=0 term) + logdet row-reduce ----
__global__ void k_fin(const float* __restrict__ x, const float* __restrict__ alph,
                      const float* __restrict__ ip, float* __restrict__ out)
{
  int row = blockIdx.x*4 + (threadIdx.x >> 6);
  int d   = threadIdx.x & 63;
  float a = (d == 0) ? ip[1] : alph[(size_t)row*64 + d];
  float s = a;
  #pragma unroll
  for (int off = 32; off; off >>= 1) s += __shfl_xor(s, off, 64);
  if (d == 0){
    out[(size_t)row*64 + 63] = (x[(size_t)row*64] - ip[0]) * __builtin_amdgcn_exp2f(-a * LOG2E);
    out[(size_t)B_N*64 + row] = -s;
  }
}

extern "C" void kernel_launch(void* const* d_in, const int* in_sizes, int n_in,
                              void* d_out, int out_size, void* d_ws, size_t ws_size,
                              hipStream_t stream)
{
  const float* x  = (const float*)d_in[0];
  const float* W1 = (const float*)d_in[1];
  const float* b1 = (const float*)d_in[2];
  const float* W2 = (const float*)d_in[3];
  const float* b2 = (const float*)d_in[4];
  const float* W3 = (const float*)d_in[5];
  const float* b3 = (const float*)d_in[6];
  const float* ip = (const float*)d_in[7];

  char* ws = (char*)d_ws;
  // w1t 1.0MB@0 | w2t 2.46MB@1MB | xbf 2MB@3.5MB | alph 4MB@5.5MB
  u16*   w1t  = (u16*)(ws);
  u16*   w2t  = (u16*)(ws + 1048576);
  u16*   xbf  = (u16*)(ws + 3670016);
  float* alph = (float*)(ws + 5767168);
  if (ws_size < 9961472) return;  // fail visibly rather than corrupt

  k_prep<<<L_N + (B_N*64/4)/256, 256, 0, stream>>>(W1, b1, W2, b2, x,
                                                   w1t, w2t, xbf);

  dim3 grid(B_N/128, L_N);
  k_main<<<grid, 256, 0, stream>>>(w1t, w2t, xbf, x, W3, b3,
                                   (float*)d_out, alph);

  k_fin<<<B_N/4, 256, 0, stream>>>(x, alph, ip, (float*)d_out);
}